// Round 13
// baseline (271.775 us; speedup 1.0000x reference)
//
#include <hip/hip_runtime.h>

#define NN 50000
#define NE 600000
#define NB 512
#define HD 128
#define NMETA 27
#define CAP 64   // bucket slots per dst (Poisson(12) max-degree ~30; 64 = safe + 128B-aligned)

typedef __attribute__((ext_vector_type(8))) short short8;            // 8 bf16 (16B)
typedef __attribute__((ext_vector_type(8))) unsigned short ushort8v; // 8 u16 (16B)
typedef __attribute__((ext_vector_type(4))) float f32x4;             // C/D frag

__device__ __forceinline__ float relu(float x) { return fmaxf(x, 0.0f); }

// fp32 -> bf16 round-to-nearest-even
__device__ __forceinline__ unsigned short f2bf(float f) {
    unsigned u = __float_as_uint(f);
    unsigned r = u + 0x7FFFu + ((u >> 16) & 1u);
    return (unsigned short)(r >> 16);
}
__device__ __forceinline__ float bf2f(unsigned short v) {
    return __uint_as_float(((unsigned)v) << 16);
}
__device__ __forceinline__ float dinv_of(int c) { return rsqrtf((float)c + 1.0f); }

// ---------------- fused: W-cast (blocks 0..191) + bucket-CSR build (rest) ----------------
__global__ __launch_bounds__(256) void k_buildcast(const int* __restrict__ src, const int* __restrict__ dst,
                                                   int* __restrict__ cnt, unsigned short* __restrict__ csr,
                                                   const float* __restrict__ W1, const float* __restrict__ W2,
                                                   const float* __restrict__ W3, unsigned short* __restrict__ Wt1,
                                                   unsigned short* __restrict__ Wt2, unsigned short* __restrict__ Wt3) {
    const int b = blockIdx.x;
    if (b < 192) {
        int i = b * 256 + threadIdx.x;          // [0, 3*HD*HD) exactly
        int which = i / (HD * HD);
        int r = i - which * (HD * HD);
        int k = r >> 7, n = r & 127;
        const float* W = (which == 0) ? W1 : (which == 1) ? W2 : W3;
        unsigned short* Wt = (which == 0) ? Wt1 : (which == 1) ? Wt2 : Wt3;
        Wt[n * HD + k] = f2bf(W[r]);
    } else {
        int e = (b - 192) * 256 + threadIdx.x;
        if (e < NE) {
            int s = src[e], d = dst[e];
            int pos = atomicAdd(&cnt[d], 1);
            if (pos < CAP)
                __builtin_nontemporal_store((unsigned short)s, &csr[(size_t)d * CAP + pos]);
        }
    }
}

// ---------------- layer-1 GEMM: T1' = (cast(x) @ W1) * dinv[row] ----------------
__global__ __launch_bounds__(256) void k_gemm_x(const float* __restrict__ X,
                                                const unsigned short* __restrict__ Wt,
                                                const int* __restrict__ cnt,
                                                unsigned short* __restrict__ T) {
    __shared__ unsigned short Ws[HD * HD];      // 32 KB
    char* wsb = (char*)Ws;
    for (int i = threadIdx.x; i < HD * HD / 8; i += 256) {
        short8 v = ((const short8*)Wt)[i];
        int byte = i * 16;
        *(short8*)(wsb + (byte ^ (((byte >> 8) & 7) << 4))) = v;
    }
    __syncthreads();

    const int wave = threadIdx.x >> 6;
    const int lane = threadIdx.x & 63;
    const int lr = lane & 15;
    const int kh = lane >> 4;
    const int r0 = blockIdx.x * 64 + wave * 16;
    const float* arow = X + (size_t)min(r0 + lr, NN - 1) * HD + kh * 8;

    f32x4 acc[8] = {};
#pragma unroll
    for (int kk = 0; kk < 4; ++kk) {
        float4 a0 = *reinterpret_cast<const float4*>(arow + kk * 32);
        float4 a1 = *reinterpret_cast<const float4*>(arow + kk * 32 + 4);
        short8 af;
        af[0] = (short)f2bf(a0.x); af[1] = (short)f2bf(a0.y);
        af[2] = (short)f2bf(a0.z); af[3] = (short)f2bf(a0.w);
        af[4] = (short)f2bf(a1.x); af[5] = (short)f2bf(a1.y);
        af[6] = (short)f2bf(a1.z); af[7] = (short)f2bf(a1.w);
#pragma unroll
        for (int n = 0; n < 8; ++n) {
            int byte = (n * 16 + lr) * 256 + kk * 64 + kh * 16;
            short8 bf = *(const short8*)(wsb + (byte ^ (((byte >> 8) & 7) << 4)));
            acc[n] = __builtin_amdgcn_mfma_f32_16x16x32_bf16(af, bf, acc[n], 0, 0, 0);
        }
    }
    float dv[4];
#pragma unroll
    for (int r = 0; r < 4; ++r) {
        int row = r0 + kh * 4 + r;
        dv[r] = (row < NN) ? dinv_of(cnt[row]) : 0.0f;
    }
#pragma unroll
    for (int n = 0; n < 8; ++n) {
#pragma unroll
        for (int r = 0; r < 4; ++r) {
            int row = r0 + kh * 4 + r;
            if (row < NN) T[(size_t)row * HD + n * 16 + lr] = f2bf(acc[n][r] * dv[r]);
        }
    }
}

// ---------------- fused gather -> {GEMM | POOL} ----------------
// 512 thr = 8 waves, 32 rows/block, grid = ceil(NN/32) = 1563.
// Gather: 16 lanes/row, one 16B row-chunk per lane per edge; edges in 8-groups
// (one ushort8 index broadcast + 8 independent row loads in flight), 4-group + singles tail.
// Only slots < deg are ever dereferenced (full groups guarantee validity).
// MODE 1: H (bf16, swizzled LDS) -> T_out' = (H @ Wt)*dinv  (NT stores)
// MODE 2: H (fp32, padded LDS) -> sorted-batch segment-reduce -> atomicAdd embsum
template <int MODE>
__global__ __launch_bounds__(512, 6) void k_fused(const int* __restrict__ cnt, const unsigned short* __restrict__ csr,
                                                  const unsigned short* __restrict__ Tin,
                                                  const float* __restrict__ b, const unsigned short* __restrict__ Wt,
                                                  unsigned short* __restrict__ Out, const int* __restrict__ batch,
                                                  float* __restrict__ embsum) {
    __shared__ char smem[32 * 132 * 4 + 128];   // fp32 padded tile + sg[32]
    char* hsb = smem;                            // MODE1: bf16 swizzled in first 8KB
    float* hsf = (float*)smem;                   // MODE2: [32][132] fp32
    int* sg = (int*)(smem + 32 * 132 * 4);

    const int rl  = threadIdx.x >> 4;           // 0..31 row within tile
    const int l16 = threadIdx.x & 15;
    const int row = blockIdx.x * 32 + rl;
    const int c   = l16 * 8;                    // 8 consecutive cols, 16B

    if (MODE == 2 && threadIdx.x < 32) {
        int rr = blockIdx.x * 32 + threadIdx.x;
        sg[threadIdx.x] = (rr < NN) ? batch[rr] : -1;
    }

    float acc[8] = {};

    if (row < NN) {
        const int deg = min(cnt[row], CAP);
        const unsigned short* eb = csr + (size_t)row * CAP;
        int j = 0;
        const int nfull = deg & ~7;
        for (; j < nfull; j += 8) {
            ushort8v iv = __builtin_nontemporal_load(reinterpret_cast<const ushort8v*>(eb + j));
            short8 t0 = *reinterpret_cast<const short8*>(Tin + (size_t)iv[0] * HD + c);
            short8 t1 = *reinterpret_cast<const short8*>(Tin + (size_t)iv[1] * HD + c);
            short8 t2 = *reinterpret_cast<const short8*>(Tin + (size_t)iv[2] * HD + c);
            short8 t3 = *reinterpret_cast<const short8*>(Tin + (size_t)iv[3] * HD + c);
            short8 t4 = *reinterpret_cast<const short8*>(Tin + (size_t)iv[4] * HD + c);
            short8 t5 = *reinterpret_cast<const short8*>(Tin + (size_t)iv[5] * HD + c);
            short8 t6 = *reinterpret_cast<const short8*>(Tin + (size_t)iv[6] * HD + c);
            short8 t7 = *reinterpret_cast<const short8*>(Tin + (size_t)iv[7] * HD + c);
#pragma unroll
            for (int i = 0; i < 8; ++i) {
                float s01 = bf2f((unsigned short)t0[i]) + bf2f((unsigned short)t1[i]);
                float s23 = bf2f((unsigned short)t2[i]) + bf2f((unsigned short)t3[i]);
                float s45 = bf2f((unsigned short)t4[i]) + bf2f((unsigned short)t5[i]);
                float s67 = bf2f((unsigned short)t6[i]) + bf2f((unsigned short)t7[i]);
                acc[i] += (s01 + s23) + (s45 + s67);
            }
        }
        if (j + 3 < deg) {
            short8 t0 = *reinterpret_cast<const short8*>(Tin + (size_t)eb[j + 0] * HD + c);
            short8 t1 = *reinterpret_cast<const short8*>(Tin + (size_t)eb[j + 1] * HD + c);
            short8 t2 = *reinterpret_cast<const short8*>(Tin + (size_t)eb[j + 2] * HD + c);
            short8 t3 = *reinterpret_cast<const short8*>(Tin + (size_t)eb[j + 3] * HD + c);
#pragma unroll
            for (int i = 0; i < 8; ++i) {
                float s01 = bf2f((unsigned short)t0[i]) + bf2f((unsigned short)t1[i]);
                float s23 = bf2f((unsigned short)t2[i]) + bf2f((unsigned short)t3[i]);
                acc[i] += s01 + s23;
            }
            j += 4;
        }
        for (; j < deg; ++j) {
            short8 tv = *reinterpret_cast<const short8*>(Tin + (size_t)eb[j] * HD + c);
#pragma unroll
            for (int i = 0; i < 8; ++i) acc[i] += bf2f((unsigned short)tv[i]);
        }
        const float di = dinv_of(deg);
        short8 ts = *reinterpret_cast<const short8*>(Tin + (size_t)row * HD + c);
        float4 bb0 = *reinterpret_cast<const float4*>(b + c);
        float4 bb1 = *reinterpret_cast<const float4*>(b + c + 4);
        float h[8];
#pragma unroll
        for (int i = 0; i < 8; ++i) {
            float bbv = (i < 4) ? (&bb0.x)[i] : (&bb1.x)[i - 4];
            h[i] = relu(fmaf(di, acc[i] + bf2f((unsigned short)ts[i]), bbv));
        }
        if (MODE == 1) {
            short8 o;
#pragma unroll
            for (int i = 0; i < 8; ++i) o[i] = (short)f2bf(h[i]);
            int byte0 = rl * 256 + c * 2;       // 16B aligned
            *(short8*)(hsb + (byte0 ^ (((byte0 >> 8) & 7) << 4))) = o;
        } else {
            *(float4*)(&hsf[rl * 132 + c])     = make_float4(h[0], h[1], h[2], h[3]);
            *(float4*)(&hsf[rl * 132 + c + 4]) = make_float4(h[4], h[5], h[6], h[7]);
        }
    } else {
        if (MODE == 1) {
            short8 z = {0, 0, 0, 0, 0, 0, 0, 0};
            int byte0 = rl * 256 + c * 2;
            *(short8*)(hsb + (byte0 ^ (((byte0 >> 8) & 7) << 4))) = z;
        } else {
            float4 z = make_float4(0.f, 0.f, 0.f, 0.f);
            *(float4*)(&hsf[rl * 132 + c])     = z;
            *(float4*)(&hsf[rl * 132 + c + 4]) = z;
        }
    }
    __syncthreads();

    if (MODE == 1) {
        // T_out' = (H @ Wt) * dinv ; NT stores keep Out stream out of the gather-hot L2
        const int w = threadIdx.x >> 6;       // col-tile 0..7
        const int lane = threadIdx.x & 63;
        const int lr = lane & 15;
        const int kh = lane >> 4;
        f32x4 acc0 = {}, acc1 = {};
#pragma unroll
        for (int kk = 0; kk < 4; ++kk) {
            short8 bf = *reinterpret_cast<const short8*>(Wt + (size_t)(w * 16 + lr) * HD + kk * 32 + kh * 8);
            int byteA = lr * 256 + kk * 64 + kh * 16;
            int byteB = (16 + lr) * 256 + kk * 64 + kh * 16;
            short8 af0 = *(const short8*)(hsb + (byteA ^ (((byteA >> 8) & 7) << 4)));
            short8 af1 = *(const short8*)(hsb + (byteB ^ (((byteB >> 8) & 7) << 4)));
            acc0 = __builtin_amdgcn_mfma_f32_16x16x32_bf16(af0, bf, acc0, 0, 0, 0);
            acc1 = __builtin_amdgcn_mfma_f32_16x16x32_bf16(af1, bf, acc1, 0, 0, 0);
        }
#pragma unroll
        for (int r = 0; r < 4; ++r) {
            int row0 = blockIdx.x * 32 + kh * 4 + r;
            int row1 = row0 + 16;
            if (row0 < NN)
                __builtin_nontemporal_store(f2bf(acc0[r] * dinv_of(cnt[row0])), &Out[(size_t)row0 * HD + w * 16 + lr]);
            if (row1 < NN)
                __builtin_nontemporal_store(f2bf(acc1[r] * dinv_of(cnt[row1])), &Out[(size_t)row1 * HD + w * 16 + lr]);
        }
    } else {
        // segment-reduce 32 sorted rows -> atomicAdd into embsum
        if (threadIdx.x < HD) {
            const int cc = threadIdx.x;
            float a = 0.f;
            int gcur = -1;
#pragma unroll 8
            for (int r = 0; r < 32; ++r) {
                int g = sg[r];
                if (g != gcur) {
                    if (gcur >= 0) atomicAdd(&embsum[gcur * HD + cc], a);
                    a = 0.f;
                    gcur = g;
                }
                a += hsf[r * 132 + cc];
            }
            if (gcur >= 0) atomicAdd(&embsum[gcur * HD + cc], a);
        }
    }
}

// ---------------- head ----------------
__global__ __launch_bounds__(128) void k_head(const float* __restrict__ embsum, const int* __restrict__ batch,
                                              const float* __restrict__ meta,
                                              const float* __restrict__ Wh1, const float* __restrict__ bh1,
                                              const float* __restrict__ Wh2, const float* __restrict__ bh2,
                                              float* __restrict__ out) {
    int g = blockIdx.x;
    int c = threadIdx.x;
    int l = 0, r = NN;
    while (l < r) { int m = (l + r) >> 1; if (batch[m] < g) l = m + 1; else r = m; }
    int lo = l;
    r = NN;
    while (l < r) { int m = (l + r) >> 1; if (batch[m] < g + 1) l = m + 1; else r = m; }
    int hi = l;
    float rcp = 1.0f / (float)max(hi - lo, 1);

    __shared__ float emb[HD];
    __shared__ float mt[NMETA];
    emb[c] = embsum[g * HD + c] * rcp;
    if (c < NMETA) mt[c] = meta[g * NMETA + c];
    __syncthreads();

    float z = bh1[c];
    float z0 = 0.f, z1 = 0.f, z2 = 0.f, z3 = 0.f;
    for (int k = 0; k < HD; k += 4) {
        z0 = fmaf(emb[k],     Wh1[k * HD + c],       z0);
        z1 = fmaf(emb[k + 1], Wh1[(k + 1) * HD + c], z1);
        z2 = fmaf(emb[k + 2], Wh1[(k + 2) * HD + c], z2);
        z3 = fmaf(emb[k + 3], Wh1[(k + 3) * HD + c], z3);
    }
    for (int k = 0; k < NMETA; ++k) z = fmaf(mt[k], Wh1[(HD + k) * HD + c], z);
    z += (z0 + z1) + (z2 + z3);
    z = relu(z);
    __shared__ float red[HD];
    red[c] = z * Wh2[c];
    __syncthreads();
    for (int st = 64; st > 0; st >>= 1) {
        if (c < st) red[c] += red[c + st];
        __syncthreads();
    }
    if (c == 0) out[g] = red[0] + bh2[0];
}

extern "C" void kernel_launch(void* const* d_in, const int* in_sizes, int n_in,
                              void* d_out, int out_size, void* d_ws, size_t ws_size,
                              hipStream_t stream) {
    const float* x     = (const float*)d_in[0];
    const int*   ei    = (const int*)d_in[1];
    const int*   src   = ei;
    const int*   dst   = ei + NE;
    const int*   batch = (const int*)d_in[2];
    const float* meta  = (const float*)d_in[3];
    const float* W1 = (const float*)d_in[4];  const float* b1 = (const float*)d_in[5];
    const float* W2 = (const float*)d_in[6];  const float* b2 = (const float*)d_in[7];
    const float* W3 = (const float*)d_in[8];  const float* b3 = (const float*)d_in[9];
    const float* Wh1 = (const float*)d_in[10]; const float* bh1 = (const float*)d_in[11];
    const float* Wh2 = (const float*)d_in[12]; const float* bh2 = (const float*)d_in[13];
    float* out = (float*)d_out;

    // workspace layout (16B-aligned sections); cnt+embsum contiguous -> one memset
    int*   cnt    = (int*)d_ws;                            // NN ints
    float* embsum = (float*)(cnt + NN);                    // NB*HD f32
    unsigned short* csr = (unsigned short*)(embsum + NB * HD);        // NN*CAP u16 (6.4MB)
    unsigned short* Ta  = csr + (size_t)NN * CAP;                     // NN*HD bf16
    unsigned short* Tc  = Ta + (size_t)NN * HD;                       // NN*HD bf16
    unsigned short* Wt1 = Tc + (size_t)NN * HD;                       // HD*HD bf16
    unsigned short* Wt2 = Wt1 + HD * HD;
    unsigned short* Wt3 = Wt2 + HD * HD;

    const int GEMM_GRID  = (NN + 63) / 64;                // 782
    const int FUSED_GRID = (NN + 31) / 32;                // 1563
    const int BC_GRID    = 192 + (NE + 255) / 256;        // 192 cast + 2344 build

    // zero cnt+embsum; build bucket-CSR + cast weights in one kernel
    hipMemsetAsync(cnt, 0, NN * sizeof(int) + NB * HD * sizeof(float), stream);
    k_buildcast<<<BC_GRID, 256, 0, stream>>>(src, dst, cnt, csr, W1, W2, W3, Wt1, Wt2, Wt3);

    // layer 1: T1' = (cast(x) @ W1) * dinv
    k_gemm_x<<<GEMM_GRID, 256, 0, stream>>>(x, Wt1, cnt, Ta);
    // layer 1 gather + layer 2 gemm: T2'
    k_fused<1><<<FUSED_GRID, 512, 0, stream>>>(cnt, csr, Ta, b1, Wt2, Tc, nullptr, nullptr);
    // layer 2 gather + layer 3 gemm: T3'
    k_fused<1><<<FUSED_GRID, 512, 0, stream>>>(cnt, csr, Tc, b2, Wt3, Ta, nullptr, nullptr);
    // layer 3 gather + pooled segment-sum into embsum
    k_fused<2><<<FUSED_GRID, 512, 0, stream>>>(cnt, csr, Ta, b3, nullptr, nullptr, batch, embsum);

    // head
    k_head<<<NB, 128, 0, stream>>>(embsum, batch, meta, Wh1, bh1, Wh2, bh2, out);
}

// Round 14
// 260.139 us; speedup vs baseline: 1.0447x; 1.0447x over previous
//
#include <hip/hip_runtime.h>

#define NN 50000
#define NE 600000
#define NB 512
#define HD 128
#define NMETA 27
#define CAP 64   // bucket slots per dst (Poisson(12) max-degree ~30; 64 = safe, 128B rows)

typedef __attribute__((ext_vector_type(8))) short short8;   // 8 bf16 (16B)
typedef __attribute__((ext_vector_type(4))) float f32x4;    // C/D frag

__device__ __forceinline__ float relu(float x) { return fmaxf(x, 0.0f); }

// fp32 -> bf16 round-to-nearest-even
__device__ __forceinline__ unsigned short f2bf(float f) {
    unsigned u = __float_as_uint(f);
    unsigned r = u + 0x7FFFu + ((u >> 16) & 1u);
    return (unsigned short)(r >> 16);
}
__device__ __forceinline__ float bf2f(unsigned short v) {
    return __uint_as_float(((unsigned)v) << 16);
}
__device__ __forceinline__ float dinv_of(int c) { return rsqrtf((float)c + 1.0f); }

// ---------------- fused: W-cast (blocks 0..191) + bucket-CSR build (rest) ----------------
__global__ __launch_bounds__(256) void k_buildcast(const int* __restrict__ src, const int* __restrict__ dst,
                                                   int* __restrict__ cnt, unsigned short* __restrict__ csr,
                                                   const float* __restrict__ W1, const float* __restrict__ W2,
                                                   const float* __restrict__ W3, unsigned short* __restrict__ Wt1,
                                                   unsigned short* __restrict__ Wt2, unsigned short* __restrict__ Wt3) {
    const int b = blockIdx.x;
    if (b < 192) {
        int i = b * 256 + threadIdx.x;          // [0, 3*HD*HD) exactly
        int which = i / (HD * HD);
        int r = i - which * (HD * HD);
        int k = r >> 7, n = r & 127;
        const float* W = (which == 0) ? W1 : (which == 1) ? W2 : W3;
        unsigned short* Wt = (which == 0) ? Wt1 : (which == 1) ? Wt2 : Wt3;
        Wt[n * HD + k] = f2bf(W[r]);
    } else {
        int e = (b - 192) * 256 + threadIdx.x;
        if (e < NE) {
            int s = src[e], d = dst[e];
            int pos = atomicAdd(&cnt[d], 1);
            if (pos < CAP) csr[(size_t)d * CAP + pos] = (unsigned short)s;
        }
    }
}

// ---------------- layer-1 GEMM: T1' = (cast(x) @ W1) * dinv[row] ----------------
__global__ __launch_bounds__(256) void k_gemm_x(const float* __restrict__ X,
                                                const unsigned short* __restrict__ Wt,
                                                const int* __restrict__ cnt,
                                                unsigned short* __restrict__ T) {
    __shared__ unsigned short Ws[HD * HD];      // 32 KB
    char* wsb = (char*)Ws;
    for (int i = threadIdx.x; i < HD * HD / 8; i += 256) {
        short8 v = ((const short8*)Wt)[i];
        int byte = i * 16;
        *(short8*)(wsb + (byte ^ (((byte >> 8) & 7) << 4))) = v;
    }
    __syncthreads();

    const int wave = threadIdx.x >> 6;
    const int lane = threadIdx.x & 63;
    const int lr = lane & 15;
    const int kh = lane >> 4;
    const int r0 = blockIdx.x * 64 + wave * 16;
    const float* arow = X + (size_t)min(r0 + lr, NN - 1) * HD + kh * 8;

    f32x4 acc[8] = {};
#pragma unroll
    for (int kk = 0; kk < 4; ++kk) {
        float4 a0 = *reinterpret_cast<const float4*>(arow + kk * 32);
        float4 a1 = *reinterpret_cast<const float4*>(arow + kk * 32 + 4);
        short8 af;
        af[0] = (short)f2bf(a0.x); af[1] = (short)f2bf(a0.y);
        af[2] = (short)f2bf(a0.z); af[3] = (short)f2bf(a0.w);
        af[4] = (short)f2bf(a1.x); af[5] = (short)f2bf(a1.y);
        af[6] = (short)f2bf(a1.z); af[7] = (short)f2bf(a1.w);
#pragma unroll
        for (int n = 0; n < 8; ++n) {
            int byte = (n * 16 + lr) * 256 + kk * 64 + kh * 16;
            short8 bf = *(const short8*)(wsb + (byte ^ (((byte >> 8) & 7) << 4)));
            acc[n] = __builtin_amdgcn_mfma_f32_16x16x32_bf16(af, bf, acc[n], 0, 0, 0);
        }
    }
    float dv[4];
#pragma unroll
    for (int r = 0; r < 4; ++r) {
        int row = r0 + kh * 4 + r;
        dv[r] = (row < NN) ? dinv_of(cnt[row]) : 0.0f;
    }
#pragma unroll
    for (int n = 0; n < 8; ++n) {
#pragma unroll
        for (int r = 0; r < 4; ++r) {
            int row = r0 + kh * 4 + r;
            if (row < NN) T[(size_t)row * HD + n * 16 + lr] = f2bf(acc[n][r] * dv[r]);
        }
    }
}

// ---------------- fused gather -> {GEMM | POOL}  (round-12 proven schedule) ----------------
// 512 thr = 8 waves, 32 rows/block, grid = ceil(NN/32) = 1563.
// Gather: 16 lanes/row, ONE 16B load per lane per edge; 4-edge two-deep pipeline.
// H[row] = relu( dinv[row]*(sum_e T'[src_e] + T'[row]) + b ), T' pre-scaled.
// MODE 1: H (bf16, swizzled LDS) -> T_out' = (H @ Wt)*dinv  (2 row-tiles x 8 col-tiles)
// MODE 2: H (fp32, padded LDS) -> sorted-batch segment-reduce -> atomicAdd embsum
template <int MODE>
__global__ __launch_bounds__(512, 8) void k_fused(const int* __restrict__ cnt, const unsigned short* __restrict__ csr,
                                                  const unsigned short* __restrict__ Tin,
                                                  const float* __restrict__ b, const unsigned short* __restrict__ Wt,
                                                  unsigned short* __restrict__ Out, const int* __restrict__ batch,
                                                  float* __restrict__ embsum) {
    __shared__ char smem[32 * 132 * 4 + 128];   // fp32 padded tile + sg[32]
    char* hsb = smem;                            // MODE1: bf16 swizzled in first 8KB
    float* hsf = (float*)smem;                   // MODE2: [32][132] fp32
    int* sg = (int*)(smem + 32 * 132 * 4);

    const int rl  = threadIdx.x >> 4;           // 0..31 row within tile
    const int l16 = threadIdx.x & 15;
    const int row = blockIdx.x * 32 + rl;
    const int c   = l16 * 8;                    // 8 consecutive cols, 16B

    if (MODE == 2 && threadIdx.x < 32) {
        int rr = blockIdx.x * 32 + threadIdx.x;
        sg[threadIdx.x] = (rr < NN) ? batch[rr] : -1;
    }

    float acc[8] = {};

    if (row < NN) {
        const int deg = min(cnt[row], CAP);
        const unsigned short* eb = csr + (size_t)row * CAP;
        int j = 0;
        int sA0, sA1, sA2, sA3, sB0, sB1, sB2, sB3;
        bool haveA = (j + 3 < deg);
        if (haveA) { sA0 = eb[j]; sA1 = eb[j + 1]; sA2 = eb[j + 2]; sA3 = eb[j + 3]; }
        while (haveA) {
            const int jn = j + 4;
            const bool haveB = (jn + 3 < deg);
            if (haveB) { sB0 = eb[jn]; sB1 = eb[jn + 1]; sB2 = eb[jn + 2]; sB3 = eb[jn + 3]; }
            short8 t0 = *reinterpret_cast<const short8*>(Tin + (size_t)sA0 * HD + c);
            short8 t1 = *reinterpret_cast<const short8*>(Tin + (size_t)sA1 * HD + c);
            short8 t2 = *reinterpret_cast<const short8*>(Tin + (size_t)sA2 * HD + c);
            short8 t3 = *reinterpret_cast<const short8*>(Tin + (size_t)sA3 * HD + c);
#pragma unroll
            for (int i = 0; i < 8; ++i) {
                float s01 = bf2f((unsigned short)t0[i]) + bf2f((unsigned short)t1[i]);
                float s23 = bf2f((unsigned short)t2[i]) + bf2f((unsigned short)t3[i]);
                acc[i] += s01 + s23;
            }
            j = jn;
            sA0 = sB0; sA1 = sB1; sA2 = sB2; sA3 = sB3;
            haveA = haveB;
        }
        for (; j < deg; ++j) {
            short8 tv = *reinterpret_cast<const short8*>(Tin + (size_t)eb[j] * HD + c);
#pragma unroll
            for (int i = 0; i < 8; ++i) acc[i] += bf2f((unsigned short)tv[i]);
        }
        const float di = dinv_of(deg);
        short8 ts = *reinterpret_cast<const short8*>(Tin + (size_t)row * HD + c);
        float4 bb0 = *reinterpret_cast<const float4*>(b + c);
        float4 bb1 = *reinterpret_cast<const float4*>(b + c + 4);
        float h[8];
#pragma unroll
        for (int i = 0; i < 8; ++i) {
            float bbv = (i < 4) ? (&bb0.x)[i] : (&bb1.x)[i - 4];
            h[i] = relu(fmaf(di, acc[i] + bf2f((unsigned short)ts[i]), bbv));
        }
        if (MODE == 1) {
            short8 o;
#pragma unroll
            for (int i = 0; i < 8; ++i) o[i] = (short)f2bf(h[i]);
            int byte0 = rl * 256 + c * 2;       // 16B aligned
            *(short8*)(hsb + (byte0 ^ (((byte0 >> 8) & 7) << 4))) = o;
        } else {
            *(float4*)(&hsf[rl * 132 + c])     = make_float4(h[0], h[1], h[2], h[3]);
            *(float4*)(&hsf[rl * 132 + c + 4]) = make_float4(h[4], h[5], h[6], h[7]);
        }
    } else {
        if (MODE == 1) {
            short8 z = {0, 0, 0, 0, 0, 0, 0, 0};
            int byte0 = rl * 256 + c * 2;
            *(short8*)(hsb + (byte0 ^ (((byte0 >> 8) & 7) << 4))) = z;
        } else {
            float4 z = make_float4(0.f, 0.f, 0.f, 0.f);
            *(float4*)(&hsf[rl * 132 + c])     = z;
            *(float4*)(&hsf[rl * 132 + c + 4]) = z;
        }
    }
    __syncthreads();

    if (MODE == 1) {
        // T_out' = (H @ Wt) * dinv
        const int w = threadIdx.x >> 6;       // col-tile 0..7
        const int lane = threadIdx.x & 63;
        const int lr = lane & 15;
        const int kh = lane >> 4;
        f32x4 acc0 = {}, acc1 = {};
#pragma unroll
        for (int kk = 0; kk < 4; ++kk) {
            short8 bf = *reinterpret_cast<const short8*>(Wt + (size_t)(w * 16 + lr) * HD + kk * 32 + kh * 8);
            int byteA = lr * 256 + kk * 64 + kh * 16;
            int byteB = (16 + lr) * 256 + kk * 64 + kh * 16;
            short8 af0 = *(const short8*)(hsb + (byteA ^ (((byteA >> 8) & 7) << 4)));
            short8 af1 = *(const short8*)(hsb + (byteB ^ (((byteB >> 8) & 7) << 4)));
            acc0 = __builtin_amdgcn_mfma_f32_16x16x32_bf16(af0, bf, acc0, 0, 0, 0);
            acc1 = __builtin_amdgcn_mfma_f32_16x16x32_bf16(af1, bf, acc1, 0, 0, 0);
        }
#pragma unroll
        for (int r = 0; r < 4; ++r) {
            int row0 = blockIdx.x * 32 + kh * 4 + r;
            int row1 = row0 + 16;
            if (row0 < NN) Out[(size_t)row0 * HD + w * 16 + lr] = f2bf(acc0[r] * dinv_of(cnt[row0]));
            if (row1 < NN) Out[(size_t)row1 * HD + w * 16 + lr] = f2bf(acc1[r] * dinv_of(cnt[row1]));
        }
    } else {
        // segment-reduce 32 sorted rows -> atomicAdd into embsum
        if (threadIdx.x < HD) {
            const int cc = threadIdx.x;
            float a = 0.f;
            int gcur = -1;
#pragma unroll 8
            for (int r = 0; r < 32; ++r) {
                int g = sg[r];
                if (g != gcur) {
                    if (gcur >= 0) atomicAdd(&embsum[gcur * HD + cc], a);
                    a = 0.f;
                    gcur = g;
                }
                a += hsf[r * 132 + cc];
            }
            if (gcur >= 0) atomicAdd(&embsum[gcur * HD + cc], a);
        }
    }
}

// ---------------- head ----------------
__global__ __launch_bounds__(128) void k_head(const float* __restrict__ embsum, const int* __restrict__ batch,
                                              const float* __restrict__ meta,
                                              const float* __restrict__ Wh1, const float* __restrict__ bh1,
                                              const float* __restrict__ Wh2, const float* __restrict__ bh2,
                                              float* __restrict__ out) {
    int g = blockIdx.x;
    int c = threadIdx.x;
    int l = 0, r = NN;
    while (l < r) { int m = (l + r) >> 1; if (batch[m] < g) l = m + 1; else r = m; }
    int lo = l;
    r = NN;
    while (l < r) { int m = (l + r) >> 1; if (batch[m] < g + 1) l = m + 1; else r = m; }
    int hi = l;
    float rcp = 1.0f / (float)max(hi - lo, 1);

    __shared__ float emb[HD];
    __shared__ float mt[NMETA];
    emb[c] = embsum[g * HD + c] * rcp;
    if (c < NMETA) mt[c] = meta[g * NMETA + c];
    __syncthreads();

    float z = bh1[c];
    float z0 = 0.f, z1 = 0.f, z2 = 0.f, z3 = 0.f;
    for (int k = 0; k < HD; k += 4) {
        z0 = fmaf(emb[k],     Wh1[k * HD + c],       z0);
        z1 = fmaf(emb[k + 1], Wh1[(k + 1) * HD + c], z1);
        z2 = fmaf(emb[k + 2], Wh1[(k + 2) * HD + c], z2);
        z3 = fmaf(emb[k + 3], Wh1[(k + 3) * HD + c], z3);
    }
    for (int k = 0; k < NMETA; ++k) z = fmaf(mt[k], Wh1[(HD + k) * HD + c], z);
    z += (z0 + z1) + (z2 + z3);
    z = relu(z);
    __shared__ float red[HD];
    red[c] = z * Wh2[c];
    __syncthreads();
    for (int st = 64; st > 0; st >>= 1) {
        if (c < st) red[c] += red[c + st];
        __syncthreads();
    }
    if (c == 0) out[g] = red[0] + bh2[0];
}

extern "C" void kernel_launch(void* const* d_in, const int* in_sizes, int n_in,
                              void* d_out, int out_size, void* d_ws, size_t ws_size,
                              hipStream_t stream) {
    const float* x     = (const float*)d_in[0];
    const int*   ei    = (const int*)d_in[1];
    const int*   src   = ei;
    const int*   dst   = ei + NE;
    const int*   batch = (const int*)d_in[2];
    const float* meta  = (const float*)d_in[3];
    const float* W1 = (const float*)d_in[4];  const float* b1 = (const float*)d_in[5];
    const float* W2 = (const float*)d_in[6];  const float* b2 = (const float*)d_in[7];
    const float* W3 = (const float*)d_in[8];  const float* b3 = (const float*)d_in[9];
    const float* Wh1 = (const float*)d_in[10]; const float* bh1 = (const float*)d_in[11];
    const float* Wh2 = (const float*)d_in[12]; const float* bh2 = (const float*)d_in[13];
    float* out = (float*)d_out;

    // workspace layout (16B-aligned sections); cnt+embsum contiguous -> one memset
    int*   cnt    = (int*)d_ws;                            // NN ints
    float* embsum = (float*)(cnt + NN);                    // NB*HD f32
    unsigned short* csr = (unsigned short*)(embsum + NB * HD);        // NN*CAP u16 (6.4MB)
    unsigned short* Ta  = csr + (size_t)NN * CAP;                     // NN*HD bf16
    unsigned short* Tc  = Ta + (size_t)NN * HD;                       // NN*HD bf16
    unsigned short* Wt1 = Tc + (size_t)NN * HD;                       // HD*HD bf16
    unsigned short* Wt2 = Wt1 + HD * HD;
    unsigned short* Wt3 = Wt2 + HD * HD;

    const int GEMM_GRID  = (NN + 63) / 64;                // 782
    const int FUSED_GRID = (NN + 31) / 32;                // 1563
    const int BC_GRID    = 192 + (NE + 255) / 256;        // 192 cast + 2344 build

    // zero cnt+embsum; build bucket-CSR + cast weights in one kernel
    hipMemsetAsync(cnt, 0, NN * sizeof(int) + NB * HD * sizeof(float), stream);
    k_buildcast<<<BC_GRID, 256, 0, stream>>>(src, dst, cnt, csr, W1, W2, W3, Wt1, Wt2, Wt3);

    // layer 1: T1' = (cast(x) @ W1) * dinv
    k_gemm_x<<<GEMM_GRID, 256, 0, stream>>>(x, Wt1, cnt, Ta);
    // layer 1 gather + layer 2 gemm: T2'
    k_fused<1><<<FUSED_GRID, 512, 0, stream>>>(cnt, csr, Ta, b1, Wt2, Tc, nullptr, nullptr);
    // layer 2 gather + layer 3 gemm: T3'
    k_fused<1><<<FUSED_GRID, 512, 0, stream>>>(cnt, csr, Tc, b2, Wt3, Ta, nullptr, nullptr);
    // layer 3 gather + pooled segment-sum into embsum
    k_fused<2><<<FUSED_GRID, 512, 0, stream>>>(cnt, csr, Ta, b3, nullptr, nullptr, batch, embsum);

    // head
    k_head<<<NB, 128, 0, stream>>>(embsum, batch, meta, Wh1, bh1, Wh2, bh2, out);
}